// Round 3
// baseline (434.874 us; speedup 1.0000x reference)
//
#include <hip/hip_runtime.h>
#include <cstdint>

typedef __bf16 bf16_t;
typedef __attribute__((ext_vector_type(8))) __bf16 bf16x8;
typedef __attribute__((ext_vector_type(4))) float f32x4;
typedef unsigned short ushort_t;

#define TOKENS 8192
#define DIM 1024
#define HID 4096
#define NEXP 8

__device__ __forceinline__ void gl_lds16(const void* g, void* l) {
  __builtin_amdgcn_global_load_lds(
      (__attribute__((address_space(1))) void*)(void*)g,
      (__attribute__((address_space(3))) void*)l, 16, 0, 0);
}

__device__ __forceinline__ float gelu_tanh(float x) {
  float z = 0.7978845608028654f * (x + 0.044715f * x * x * x);
  z = fminf(fmaxf(z, -15.f), 15.f);
  float e = __expf(-2.f * z);
  float th = (1.f - e) / (1.f + e);
  return 0.5f * x * (1.f + th);
}

// ---------------- router: logits/softmax/argmax/gate + partials + x->bf16 ----------------
__global__ void router_kernel(const float* __restrict__ x, const float* __restrict__ rw,
                              const float* __restrict__ rbias, bf16_t* __restrict__ xb,
                              int* __restrict__ sel, float* __restrict__ gate,
                              float* __restrict__ pprob, int* __restrict__ pcnt) {
  __shared__ float sprob[NEXP];
  __shared__ int scnt[NEXP];
  int t = threadIdx.x, lane = t & 63, wave = t >> 6;
  if (t < NEXP) { sprob[t] = 0.f; scnt[t] = 0; }
  __syncthreads();
  int tok = blockIdx.x * 4 + wave;
  const float* xp = x + (size_t)tok * DIM + lane * 16;
  float acc[NEXP];
#pragma unroll
  for (int e = 0; e < NEXP; ++e) acc[e] = 0.f;
  ushort_t xv[16];
#pragma unroll
  for (int j = 0; j < 16; j += 4) {
    float4 v = *(const float4*)(xp + j);
    const float* wr = rw + (size_t)(lane * 16 + j) * NEXP;
    float c[4] = {v.x, v.y, v.z, v.w};
#pragma unroll
    for (int d = 0; d < 4; ++d) {
      xv[j + d] = __builtin_bit_cast(ushort_t, (bf16_t)c[d]);
#pragma unroll
      for (int e = 0; e < NEXP; ++e) acc[e] += c[d] * wr[d * NEXP + e];
    }
  }
  {
    uint4* xop = (uint4*)(xb + (size_t)tok * DIM + lane * 16);
    xop[0] = ((uint4*)xv)[0];
    xop[1] = ((uint4*)xv)[1];
  }
#pragma unroll
  for (int s = 1; s < 64; s <<= 1)
#pragma unroll
    for (int e = 0; e < NEXP; ++e) acc[e] += __shfl_xor(acc[e], s);
  if (lane == 0) {
    float lg[NEXP];
#pragma unroll
    for (int e = 0; e < NEXP; ++e) lg[e] = acc[e] + rbias[e];
    float mx = lg[0]; int am = 0;
#pragma unroll
    for (int e = 1; e < NEXP; ++e) if (lg[e] > mx) { mx = lg[e]; am = e; }
    float p[NEXP]; float se = 0.f;
#pragma unroll
    for (int e = 0; e < NEXP; ++e) { p[e] = __expf(lg[e] - mx); se += p[e]; }
    float inv = 1.f / se;
#pragma unroll
    for (int e = 0; e < NEXP; ++e) { p[e] *= inv; atomicAdd(&sprob[e], p[e]); }
    sel[tok] = am;
    gate[tok] = p[am];
    atomicAdd(&scnt[am], 1);
  }
  __syncthreads();
  if (t < NEXP) {
    pprob[blockIdx.x * NEXP + t] = sprob[t];
    pcnt[blockIdx.x * NEXP + t] = scnt[t];
  }
}

// ---------------- transpose + convert both weights in one launch ----------------
__global__ void tcvt2_kernel(const float* __restrict__ w1, const float* __restrict__ w2,
                             bf16_t* __restrict__ w1t, bf16_t* __restrict__ w2t) {
  __shared__ float tile[64][65];
  int y = blockIdx.y;
  int which = y >> 3, e = y & 7;
  int R = which ? HID : DIM;
  int C = which ? DIM : HID;
  const float* src = (which ? w2 : w1) + (size_t)e * R * C;
  bf16_t* dst = (which ? w2t : w1t) + (size_t)e * R * C;
  int cbt = C >> 6;
  int rt = blockIdx.x / cbt, ct = blockIdx.x % cbt;
  int rb = rt * 64, cb = ct * 64;
  int t = threadIdx.x;
  int r = t >> 2, cq = (t & 3) * 16;
  const float* sp = src + (size_t)(rb + r) * C + cb + cq;
#pragma unroll
  for (int j = 0; j < 16; j += 4) {
    float4 v = *(const float4*)(sp + j);
    tile[r][cq + j + 0] = v.x; tile[r][cq + j + 1] = v.y;
    tile[r][cq + j + 2] = v.z; tile[r][cq + j + 3] = v.w;
  }
  __syncthreads();
  int oc = t >> 2, orr = (t & 3) * 16;
  ushort_t tmp[16];
#pragma unroll
  for (int j = 0; j < 16; ++j) {
    bf16_t b = (bf16_t)tile[orr + j][oc];
    tmp[j] = __builtin_bit_cast(ushort_t, b);
  }
  uint4* dp = (uint4*)(dst + (size_t)(cb + oc) * R + rb + orr);
  dp[0] = ((uint4*)tmp)[0];
  dp[1] = ((uint4*)tmp)[1];
}

// ---------------- reduce partials: counts, offsets, cursors, aux loss ----------------
__global__ void reduce_kernel(const float* __restrict__ pprob, const int* __restrict__ pcnt,
                              int nb, int* __restrict__ counts, int* __restrict__ offsets,
                              int* __restrict__ cursors, float* __restrict__ loss_out) {
  __shared__ float fred[256];
  __shared__ int ired[256];
  int t = threadIdx.x;
  int e = t & 7, i0 = t >> 3;
  float fs = 0.f; int is = 0;
  for (int i = i0; i < nb; i += 32) { fs += pprob[i * 8 + e]; is += pcnt[i * 8 + e]; }
  fred[t] = fs; ired[t] = is;
  __syncthreads();
  if (t < NEXP) {
    float tp = 0.f; int tc = 0;
    for (int j = 0; j < 32; ++j) { tp += fred[j * 8 + t]; tc += ired[j * 8 + t]; }
    counts[t] = tc;
    fred[t] = tp;
    cursors[t] = 0;
  }
  __syncthreads();
  if (t == 0) {
    int off = 0; float loss = 0.f;
    for (int q = 0; q < NEXP; ++q) {
      offsets[q] = off; off += counts[q];
      loss += (fred[q] / (float)TOKENS) * ((float)counts[q] / (float)TOKENS);
    }
    *loss_out = loss * (float)NEXP * 0.01f;
  }
}

// ---------------- scatter token indices by expert ----------------
__global__ void scatter_kernel(const int* __restrict__ sel, const int* __restrict__ offsets,
                               int* __restrict__ cursors, int* __restrict__ idxl) {
  int tok = blockIdx.x * 256 + threadIdx.x;
  int lane = threadIdx.x & 63;
  int e = sel[tok];
#pragma unroll
  for (int ex = 0; ex < NEXP; ++ex) {
    unsigned long long mask = __ballot(e == ex);
    if (e == ex) {
      int leader = __ffsll(mask) - 1;
      int total = __popcll(mask);
      int rank = __popcll(mask & ((1ull << lane) - 1ull));
      int base = 0;
      if (lane == leader) base = atomicAdd(&cursors[ex], total);
      base = __shfl(base, leader);
      idxl[offsets[ex] + base + rank] = tok;
    }
  }
}

// ---------------- GEMM1: h = gelu(x_gather @ w1 + b1), bf16 out, 128x128 ----------------
__global__ __launch_bounds__(256) void gemm1_kernel(
    const bf16_t* __restrict__ xb, const bf16_t* __restrict__ w1t,
    const float* __restrict__ b1, const int* __restrict__ idxl,
    const int* __restrict__ counts, const int* __restrict__ offsets,
    bf16_t* __restrict__ h) {
  int e = blockIdx.z;
  int cnt = counts[e];
  int mBase = blockIdx.y * 128;
  if (mBase >= cnt) return;
  int nBase = blockIdx.x * 128;
  int off = offsets[e];
  __shared__ bf16_t As[4096], Bs[4096];
  int t = threadIdx.x, lane = t & 63, wave = t >> 6;
  int wrow = wave >> 1, wcol = wave & 1;
  f32x4 acc[4][4];
#pragma unroll
  for (int m = 0; m < 4; ++m)
#pragma unroll
    for (int n = 0; n < 4; ++n) acc[m][n] = (f32x4){0.f, 0.f, 0.f, 0.f};

  int srow = wave * 16 + (lane >> 2);
  int kin = (lane & 3) * 8;
  int c1 = cnt - 1;
  int slot0 = mBase + srow; slot0 = slot0 < c1 ? slot0 : c1;
  int slot1 = mBase + srow + 64; slot1 = slot1 < c1 ? slot1 : c1;
  int tok0 = idxl[off + slot0], tok1 = idxl[off + slot1];
  const bf16_t* ag0 = xb + (size_t)tok0 * DIM + kin;
  const bf16_t* ag1 = xb + (size_t)tok1 * DIM + kin;
  const bf16_t* wb = w1t + (size_t)e * HID * DIM;
  const bf16_t* bg0 = wb + (size_t)(nBase + srow) * DIM + kin;
  const bf16_t* bg1 = bg0 + (size_t)64 * DIM;
  bf16_t* lA0 = As + wave * 512;
  bf16_t* lA1 = As + 2048 + wave * 512;
  bf16_t* lB0 = Bs + wave * 512;
  bf16_t* lB1 = Bs + 2048 + wave * 512;
  int kcol = (lane >> 4) * 8;

  for (int kt = 0; kt < DIM / 32; ++kt) {
    int k0 = kt * 32;
    gl_lds16(ag0 + k0, lA0);
    gl_lds16(ag1 + k0, lA1);
    gl_lds16(bg0 + k0, lB0);
    gl_lds16(bg1 + k0, lB1);
    __syncthreads();
    bf16x8 af[4], bv[4];
#pragma unroll
    for (int m = 0; m < 4; ++m)
      af[m] = *(const bf16x8*)(As + (wrow * 64 + m * 16 + (lane & 15)) * 32 + kcol);
#pragma unroll
    for (int n = 0; n < 4; ++n)
      bv[n] = *(const bf16x8*)(Bs + (wcol * 64 + n * 16 + (lane & 15)) * 32 + kcol);
#pragma unroll
    for (int m = 0; m < 4; ++m)
#pragma unroll
      for (int n = 0; n < 4; ++n)
        acc[m][n] = __builtin_amdgcn_mfma_f32_16x16x32_bf16(af[m], bv[n], acc[m][n], 0, 0, 0);
    __syncthreads();
  }

  float bias[4];
#pragma unroll
  for (int n = 0; n < 4; ++n) bias[n] = b1[e * HID + nBase + wcol * 64 + n * 16 + (lane & 15)];
#pragma unroll
  for (int m = 0; m < 4; ++m) {
    int rb0 = mBase + wrow * 64 + m * 16 + (lane >> 4) * 4;
#pragma unroll
    for (int j = 0; j < 4; ++j) {
      int r = rb0 + j;
      if (r < cnt) {
        bf16_t* hp = h + (size_t)(off + r) * HID + nBase + wcol * 64 + (lane & 15);
#pragma unroll
        for (int n = 0; n < 4; ++n)
          hp[n * 16] = (bf16_t)gelu_tanh(acc[m][n][j] + bias[n]);
      }
    }
  }
}

// ---------------- GEMM2: out[tok] = gate * (h @ w2 + b2), 64x128 tile, 4 waves ----------------
__global__ __launch_bounds__(256) void gemm2_kernel(
    const bf16_t* __restrict__ h, const bf16_t* __restrict__ w2t,
    const float* __restrict__ b2, const int* __restrict__ idxl,
    const float* __restrict__ gate, const int* __restrict__ counts,
    const int* __restrict__ offsets, float* __restrict__ out) {
  int e = blockIdx.z;
  int cnt = counts[e];
  int mBase = blockIdx.y * 64;
  if (mBase >= cnt) return;
  int nBase = blockIdx.x * 128;
  int off = offsets[e];
  __shared__ bf16_t S[6144];  // rows 0..63 = A (64x32), rows 64..191 = B (128x32)
  int t = threadIdx.x, lane = t & 63, wave = t >> 6;
  int wrow = wave >> 1, wcol = wave & 1;
  f32x4 acc[2][4];
#pragma unroll
  for (int m = 0; m < 2; ++m)
#pragma unroll
    for (int n = 0; n < 4; ++n) acc[m][n] = (f32x4){0.f, 0.f, 0.f, 0.f};

  // staging: 12 chunks of 16 rows; wave w stages chunks w*3+{0,1,2}
  int c1 = cnt - 1;
  int kin = (lane & 3) * 8;
  const bf16_t* srcp[3];
  bf16_t* ldst[3];
#pragma unroll
  for (int i = 0; i < 3; ++i) {
    int c = wave * 3 + i;
    int row = c * 16 + (lane >> 2);
    const bf16_t* p;
    if (row < 64) {
      int slot = mBase + row; slot = slot < c1 ? slot : c1;
      p = h + (size_t)(off + slot) * HID + kin;
    } else {
      p = w2t + (size_t)e * DIM * HID + (size_t)(nBase + row - 64) * HID + kin;
    }
    srcp[i] = p;
    ldst[i] = S + c * 512;
  }
  int kcol = (lane >> 4) * 8;

  for (int kt = 0; kt < HID / 32; ++kt) {
    int k0 = kt * 32;
    gl_lds16(srcp[0] + k0, ldst[0]);
    gl_lds16(srcp[1] + k0, ldst[1]);
    gl_lds16(srcp[2] + k0, ldst[2]);
    __syncthreads();
    bf16x8 af[2], bv[4];
#pragma unroll
    for (int m = 0; m < 2; ++m)
      af[m] = *(const bf16x8*)(S + (wrow * 32 + m * 16 + (lane & 15)) * 32 + kcol);
#pragma unroll
    for (int n = 0; n < 4; ++n)
      bv[n] = *(const bf16x8*)(S + 2048 + (wcol * 64 + n * 16 + (lane & 15)) * 32 + kcol);
#pragma unroll
    for (int m = 0; m < 2; ++m)
#pragma unroll
      for (int n = 0; n < 4; ++n)
        acc[m][n] = __builtin_amdgcn_mfma_f32_16x16x32_bf16(af[m], bv[n], acc[m][n], 0, 0, 0);
    __syncthreads();
  }

  float bias[4];
#pragma unroll
  for (int n = 0; n < 4; ++n) bias[n] = b2[e * DIM + nBase + wcol * 64 + n * 16 + (lane & 15)];
#pragma unroll
  for (int m = 0; m < 2; ++m) {
    int rb0 = mBase + wrow * 32 + m * 16 + (lane >> 4) * 4;
#pragma unroll
    for (int j = 0; j < 4; ++j) {
      int r = rb0 + j;
      if (r < cnt) {
        int tok = idxl[off + r];
        float g = gate[tok];
        float* op = out + (size_t)tok * DIM + nBase + wcol * 64 + (lane & 15);
#pragma unroll
        for (int n = 0; n < 4; ++n)
          op[n * 16] = g * (acc[m][n][j] + bias[n]);
      }
    }
  }
}

extern "C" void kernel_launch(void* const* d_in, const int* in_sizes, int n_in,
                              void* d_out, int out_size, void* d_ws, size_t ws_size,
                              hipStream_t stream) {
  const float* hs = (const float*)d_in[0];
  const float* rw = (const float*)d_in[1];
  const float* rb = (const float*)d_in[2];
  const float* w1 = (const float*)d_in[3];
  const float* b1 = (const float*)d_in[4];
  const float* w2 = (const float*)d_in[5];
  const float* b2 = (const float*)d_in[6];
  float* out = (float*)d_out;
  char* ws = (char*)d_ws;

  // workspace layout (bytes)
  bf16_t* xb   = (bf16_t*)(ws + 0);            // 8192*1024*2       = 16,777,216
  bf16_t* w1t  = (bf16_t*)(ws + 16777216);     // 8*4096*1024*2     = 67,108,864
  bf16_t* w2t  = (bf16_t*)(ws + 83886080);     // 8*1024*4096*2     = 67,108,864
  bf16_t* hbuf = (bf16_t*)(ws + 150994944);    // (8192+128)*4096*2 = 68,157,440
  int*   sel   = (int*)  (ws + 219152384);
  float* gate  = (float*)(ws + 219185152);
  int*   idxl  = (int*)  (ws + 219217920);
  float* pprob = (float*)(ws + 219250688);
  int*   pcnt  = (int*)  (ws + 219316224);
  int*   counts  = (int*)(ws + 219381760);
  int*   offsets = counts + 8;
  int*   cursors = counts + 16;

  router_kernel<<<2048, 256, 0, stream>>>(hs, rw, rb, xb, sel, gate, pprob, pcnt);
  tcvt2_kernel<<<dim3(1024, 16), 256, 0, stream>>>(w1, w2, w1t, w2t);
  reduce_kernel<<<1, 256, 0, stream>>>(pprob, pcnt, 2048, counts, offsets, cursors,
                                       out + (out_size - 1));
  scatter_kernel<<<32, 256, 0, stream>>>(sel, offsets, cursors, idxl);
  gemm1_kernel<<<dim3(32, 64, 8), 256, 0, stream>>>(xb, w1t, b1, idxl, counts, offsets, hbuf);
  gemm2_kernel<<<dim3(8, 128, 8), 256, 0, stream>>>(hbuf, w2t, b2, idxl, gate, counts, offsets, out);
}

// Round 4
// 409.364 us; speedup vs baseline: 1.0623x; 1.0623x over previous
//
#include <hip/hip_runtime.h>
#include <cstdint>

typedef __bf16 bf16_t;
typedef __attribute__((ext_vector_type(8))) __bf16 bf16x8;
typedef __attribute__((ext_vector_type(4))) float f32x4;
typedef unsigned short ushort_t;

#define TOKENS 8192
#define DIM 1024
#define HID 4096
#define NEXP 8

__device__ __forceinline__ void gl_lds16(const void* g, void* l) {
  __builtin_amdgcn_global_load_lds(
      (__attribute__((address_space(1))) void*)(void*)g,
      (__attribute__((address_space(3))) void*)l, 16, 0, 0);
}

__device__ __forceinline__ float gelu_tanh(float x) {
  float z = 0.7978845608028654f * (x + 0.044715f * x * x * x);
  z = fminf(fmaxf(z, -15.f), 15.f);
  float e = __expf(-2.f * z);
  float th = (1.f - e) / (1.f + e);
  return 0.5f * x * (1.f + th);
}

// ---------------- router: logits/softmax/argmax/gate + partials + x->bf16 ----------------
__global__ void router_kernel(const float* __restrict__ x, const float* __restrict__ rw,
                              const float* __restrict__ rbias, bf16_t* __restrict__ xb,
                              int* __restrict__ sel, float* __restrict__ gate,
                              float* __restrict__ pprob, int* __restrict__ pcnt) {
  __shared__ float sprob[NEXP];
  __shared__ int scnt[NEXP];
  int t = threadIdx.x, lane = t & 63, wave = t >> 6;
  if (t < NEXP) { sprob[t] = 0.f; scnt[t] = 0; }
  __syncthreads();
  int tok = blockIdx.x * 4 + wave;
  const float* xp = x + (size_t)tok * DIM + lane * 16;
  float acc[NEXP];
#pragma unroll
  for (int e = 0; e < NEXP; ++e) acc[e] = 0.f;
  ushort_t xv[16];
#pragma unroll
  for (int j = 0; j < 16; j += 4) {
    float4 v = *(const float4*)(xp + j);
    const float* wr = rw + (size_t)(lane * 16 + j) * NEXP;
    float c[4] = {v.x, v.y, v.z, v.w};
#pragma unroll
    for (int d = 0; d < 4; ++d) {
      xv[j + d] = __builtin_bit_cast(ushort_t, (bf16_t)c[d]);
#pragma unroll
      for (int e = 0; e < NEXP; ++e) acc[e] += c[d] * wr[d * NEXP + e];
    }
  }
  {
    uint4* xop = (uint4*)(xb + (size_t)tok * DIM + lane * 16);
    xop[0] = ((uint4*)xv)[0];
    xop[1] = ((uint4*)xv)[1];
  }
#pragma unroll
  for (int s = 1; s < 64; s <<= 1)
#pragma unroll
    for (int e = 0; e < NEXP; ++e) acc[e] += __shfl_xor(acc[e], s);
  if (lane == 0) {
    float lg[NEXP];
#pragma unroll
    for (int e = 0; e < NEXP; ++e) lg[e] = acc[e] + rbias[e];
    float mx = lg[0]; int am = 0;
#pragma unroll
    for (int e = 1; e < NEXP; ++e) if (lg[e] > mx) { mx = lg[e]; am = e; }
    float p[NEXP]; float se = 0.f;
#pragma unroll
    for (int e = 0; e < NEXP; ++e) { p[e] = __expf(lg[e] - mx); se += p[e]; }
    float inv = 1.f / se;
#pragma unroll
    for (int e = 0; e < NEXP; ++e) { p[e] *= inv; atomicAdd(&sprob[e], p[e]); }
    sel[tok] = am;
    gate[tok] = p[am];
    atomicAdd(&scnt[am], 1);
  }
  __syncthreads();
  if (t < NEXP) {
    pprob[blockIdx.x * NEXP + t] = sprob[t];
    pcnt[blockIdx.x * NEXP + t] = scnt[t];
  }
}

// ---------------- transpose + convert both weights in one launch ----------------
__global__ void tcvt2_kernel(const float* __restrict__ w1, const float* __restrict__ w2,
                             bf16_t* __restrict__ w1t, bf16_t* __restrict__ w2t) {
  __shared__ float tile[64][65];
  int y = blockIdx.y;
  int which = y >> 3, e = y & 7;
  int R = which ? HID : DIM;
  int C = which ? DIM : HID;
  const float* src = (which ? w2 : w1) + (size_t)e * R * C;
  bf16_t* dst = (which ? w2t : w1t) + (size_t)e * R * C;
  int cbt = C >> 6;
  int rt = blockIdx.x / cbt, ct = blockIdx.x % cbt;
  int rb = rt * 64, cb = ct * 64;
  int t = threadIdx.x;
  int r = t >> 2, cq = (t & 3) * 16;
  const float* sp = src + (size_t)(rb + r) * C + cb + cq;
#pragma unroll
  for (int j = 0; j < 16; j += 4) {
    float4 v = *(const float4*)(sp + j);
    tile[r][cq + j + 0] = v.x; tile[r][cq + j + 1] = v.y;
    tile[r][cq + j + 2] = v.z; tile[r][cq + j + 3] = v.w;
  }
  __syncthreads();
  int oc = t >> 2, orr = (t & 3) * 16;
  ushort_t tmp[16];
#pragma unroll
  for (int j = 0; j < 16; ++j) {
    bf16_t b = (bf16_t)tile[orr + j][oc];
    tmp[j] = __builtin_bit_cast(ushort_t, b);
  }
  uint4* dp = (uint4*)(dst + (size_t)(cb + oc) * R + rb + orr);
  dp[0] = ((uint4*)tmp)[0];
  dp[1] = ((uint4*)tmp)[1];
}

// ---------------- reduce partials: counts, offsets, cursors, aux loss ----------------
__global__ void reduce_kernel(const float* __restrict__ pprob, const int* __restrict__ pcnt,
                              int nb, int* __restrict__ counts, int* __restrict__ offsets,
                              int* __restrict__ cursors, float* __restrict__ loss_out) {
  __shared__ float fred[256];
  __shared__ int ired[256];
  int t = threadIdx.x;
  int e = t & 7, i0 = t >> 3;
  float fs = 0.f; int is = 0;
  for (int i = i0; i < nb; i += 32) { fs += pprob[i * 8 + e]; is += pcnt[i * 8 + e]; }
  fred[t] = fs; ired[t] = is;
  __syncthreads();
  if (t < NEXP) {
    float tp = 0.f; int tc = 0;
    for (int j = 0; j < 32; ++j) { tp += fred[j * 8 + t]; tc += ired[j * 8 + t]; }
    counts[t] = tc;
    fred[t] = tp;
    cursors[t] = 0;
  }
  __syncthreads();
  if (t == 0) {
    int off = 0; float loss = 0.f;
    for (int q = 0; q < NEXP; ++q) {
      offsets[q] = off; off += counts[q];
      loss += (fred[q] / (float)TOKENS) * ((float)counts[q] / (float)TOKENS);
    }
    *loss_out = loss * (float)NEXP * 0.01f;
  }
}

// ---------------- scatter token indices by expert ----------------
__global__ void scatter_kernel(const int* __restrict__ sel, const int* __restrict__ offsets,
                               int* __restrict__ cursors, int* __restrict__ idxl) {
  int tok = blockIdx.x * 256 + threadIdx.x;
  int lane = threadIdx.x & 63;
  int e = sel[tok];
#pragma unroll
  for (int ex = 0; ex < NEXP; ++ex) {
    unsigned long long mask = __ballot(e == ex);
    if (e == ex) {
      int leader = __ffsll(mask) - 1;
      int total = __popcll(mask);
      int rank = __popcll(mask & ((1ull << lane) - 1ull));
      int base = 0;
      if (lane == leader) base = atomicAdd(&cursors[ex], total);
      base = __shfl(base, leader);
      idxl[offsets[ex] + base + rank] = tok;
    }
  }
}

// ---------------- GEMM1: h = gelu(x_gather @ w1 + b1), bf16 out, 128x128, XCD swz ----------------
__global__ __launch_bounds__(256) void gemm1_kernel(
    const bf16_t* __restrict__ xb, const bf16_t* __restrict__ w1t,
    const float* __restrict__ b1, const int* __restrict__ idxl,
    const int* __restrict__ counts, const int* __restrict__ offsets,
    bf16_t* __restrict__ h) {
  int e = blockIdx.z;
  int cnt = counts[e];
  // XCD-aware swizzle: hardware id f (x fastest, round-robin across 8 XCDs)
  // -> logical id lf so each XCD owns contiguous n-stripes (B-panel L2-resident).
  int f = blockIdx.y * 32 + blockIdx.x;        // 0..2047
  int lf = (f & 7) * 256 + (f >> 3);           // bijective (2048 % 8 == 0)
  int mt = lf & 63, nt = lf >> 6;              // m-fastest within n-stripe
  int mBase = mt * 128;
  if (mBase >= cnt) return;
  int nBase = nt * 128;
  int off = offsets[e];
  __shared__ bf16_t As[4096], Bs[4096];
  int t = threadIdx.x, lane = t & 63, wave = t >> 6;
  int wrow = wave >> 1, wcol = wave & 1;
  f32x4 acc[4][4];
#pragma unroll
  for (int m = 0; m < 4; ++m)
#pragma unroll
    for (int n = 0; n < 4; ++n) acc[m][n] = (f32x4){0.f, 0.f, 0.f, 0.f};

  int srow = wave * 16 + (lane >> 2);
  int kin = (lane & 3) * 8;
  int c1 = cnt - 1;
  int slot0 = mBase + srow; slot0 = slot0 < c1 ? slot0 : c1;
  int slot1 = mBase + srow + 64; slot1 = slot1 < c1 ? slot1 : c1;
  int tok0 = idxl[off + slot0], tok1 = idxl[off + slot1];
  const bf16_t* ag0 = xb + (size_t)tok0 * DIM + kin;
  const bf16_t* ag1 = xb + (size_t)tok1 * DIM + kin;
  const bf16_t* wb = w1t + (size_t)e * HID * DIM;
  const bf16_t* bg0 = wb + (size_t)(nBase + srow) * DIM + kin;
  const bf16_t* bg1 = bg0 + (size_t)64 * DIM;
  bf16_t* lA0 = As + wave * 512;
  bf16_t* lA1 = As + 2048 + wave * 512;
  bf16_t* lB0 = Bs + wave * 512;
  bf16_t* lB1 = Bs + 2048 + wave * 512;
  int kcol = (lane >> 4) * 8;

  for (int kt = 0; kt < DIM / 32; ++kt) {
    int k0 = kt * 32;
    gl_lds16(ag0 + k0, lA0);
    gl_lds16(ag1 + k0, lA1);
    gl_lds16(bg0 + k0, lB0);
    gl_lds16(bg1 + k0, lB1);
    __syncthreads();
    bf16x8 af[4], bv[4];
#pragma unroll
    for (int m = 0; m < 4; ++m)
      af[m] = *(const bf16x8*)(As + (wrow * 64 + m * 16 + (lane & 15)) * 32 + kcol);
#pragma unroll
    for (int n = 0; n < 4; ++n)
      bv[n] = *(const bf16x8*)(Bs + (wcol * 64 + n * 16 + (lane & 15)) * 32 + kcol);
#pragma unroll
    for (int m = 0; m < 4; ++m)
#pragma unroll
      for (int n = 0; n < 4; ++n)
        acc[m][n] = __builtin_amdgcn_mfma_f32_16x16x32_bf16(af[m], bv[n], acc[m][n], 0, 0, 0);
    __syncthreads();
  }

  float bias[4];
#pragma unroll
  for (int n = 0; n < 4; ++n) bias[n] = b1[e * HID + nBase + wcol * 64 + n * 16 + (lane & 15)];
#pragma unroll
  for (int m = 0; m < 4; ++m) {
    int rb0 = mBase + wrow * 64 + m * 16 + (lane >> 4) * 4;
#pragma unroll
    for (int j = 0; j < 4; ++j) {
      int r = rb0 + j;
      if (r < cnt) {
        bf16_t* hp = h + (size_t)(off + r) * HID + nBase + wcol * 64 + (lane & 15);
#pragma unroll
        for (int n = 0; n < 4; ++n)
          hp[n * 16] = (bf16_t)gelu_tanh(acc[m][n][j] + bias[n]);
      }
    }
  }
}

// ---------------- GEMM2: out = gate*(h @ w2 + b2), 128x128 tile, 8 waves, XCD swz ----------------
__global__ __launch_bounds__(512) void gemm2_kernel(
    const bf16_t* __restrict__ h, const bf16_t* __restrict__ w2t,
    const float* __restrict__ b2, const int* __restrict__ idxl,
    const float* __restrict__ gate, const int* __restrict__ counts,
    const int* __restrict__ offsets, float* __restrict__ out) {
  int e = blockIdx.z;
  int cnt = counts[e];
  int f = blockIdx.y * 8 + blockIdx.x;         // 0..511
  int lf = (f & 7) * 64 + (f >> 3);            // bijective (512 % 8 == 0)
  int mt = lf & 63, nt = lf >> 6;              // m-fastest within n-stripe
  int mBase = mt * 128;
  if (mBase >= cnt) return;
  int nBase = nt * 128;
  int off = offsets[e];
  __shared__ bf16_t S[8192];  // A [128][32] @0, B [128][32] @4096
  int t = threadIdx.x, lane = t & 63, wave = t >> 6;  // wave 0..7
  int wrow = wave >> 2, wcol = wave & 3;              // wave tile 64x32
  f32x4 acc[4][2];
#pragma unroll
  for (int m = 0; m < 4; ++m)
#pragma unroll
    for (int n = 0; n < 2; ++n) acc[m][n] = (f32x4){0.f, 0.f, 0.f, 0.f};

  // staging: wave w stages A rows w*16..+15 and B rows w*16..+15 (1 KB each)
  int srow = wave * 16 + (lane >> 2);
  int kin = (lane & 3) * 8;
  int c1 = cnt - 1;
  int slot = mBase + srow; slot = slot < c1 ? slot : c1;
  const bf16_t* agA = h + (size_t)(off + slot) * HID + kin;
  const bf16_t* agB = w2t + (size_t)e * DIM * HID + (size_t)(nBase + srow) * HID + kin;
  bf16_t* lA = S + wave * 512;
  bf16_t* lB = S + 4096 + wave * 512;
  int kcol = (lane >> 4) * 8;

  for (int kt = 0; kt < HID / 32; ++kt) {
    int k0 = kt * 32;
    gl_lds16(agA + k0, lA);
    gl_lds16(agB + k0, lB);
    __syncthreads();
    bf16x8 af[4], bv[2];
#pragma unroll
    for (int m = 0; m < 4; ++m)
      af[m] = *(const bf16x8*)(S + (wrow * 64 + m * 16 + (lane & 15)) * 32 + kcol);
#pragma unroll
    for (int n = 0; n < 2; ++n)
      bv[n] = *(const bf16x8*)(S + 4096 + (wcol * 32 + n * 16 + (lane & 15)) * 32 + kcol);
#pragma unroll
    for (int m = 0; m < 4; ++m)
#pragma unroll
      for (int n = 0; n < 2; ++n)
        acc[m][n] = __builtin_amdgcn_mfma_f32_16x16x32_bf16(af[m], bv[n], acc[m][n], 0, 0, 0);
    __syncthreads();
  }

  float bias[2];
#pragma unroll
  for (int n = 0; n < 2; ++n) bias[n] = b2[e * DIM + nBase + wcol * 32 + n * 16 + (lane & 15)];
#pragma unroll
  for (int m = 0; m < 4; ++m) {
    int rb0 = mBase + wrow * 64 + m * 16 + (lane >> 4) * 4;
#pragma unroll
    for (int j = 0; j < 4; ++j) {
      int r = rb0 + j;
      if (r < cnt) {
        int tok = idxl[off + r];
        float g = gate[tok];
        float* op = out + (size_t)tok * DIM + nBase + wcol * 32 + (lane & 15);
#pragma unroll
        for (int n = 0; n < 2; ++n)
          op[n * 16] = g * (acc[m][n][j] + bias[n]);
      }
    }
  }
}

extern "C" void kernel_launch(void* const* d_in, const int* in_sizes, int n_in,
                              void* d_out, int out_size, void* d_ws, size_t ws_size,
                              hipStream_t stream) {
  const float* hs = (const float*)d_in[0];
  const float* rw = (const float*)d_in[1];
  const float* rb = (const float*)d_in[2];
  const float* w1 = (const float*)d_in[3];
  const float* b1 = (const float*)d_in[4];
  const float* w2 = (const float*)d_in[5];
  const float* b2 = (const float*)d_in[6];
  float* out = (float*)d_out;
  char* ws = (char*)d_ws;

  // workspace layout (bytes)
  bf16_t* xb   = (bf16_t*)(ws + 0);            // 8192*1024*2       = 16,777,216
  bf16_t* w1t  = (bf16_t*)(ws + 16777216);     // 8*4096*1024*2     = 67,108,864
  bf16_t* w2t  = (bf16_t*)(ws + 83886080);     // 8*1024*4096*2     = 67,108,864
  bf16_t* hbuf = (bf16_t*)(ws + 150994944);    // (8192+128)*4096*2 = 68,157,440
  int*   sel   = (int*)  (ws + 219152384);
  float* gate  = (float*)(ws + 219185152);
  int*   idxl  = (int*)  (ws + 219217920);
  float* pprob = (float*)(ws + 219250688);
  int*   pcnt  = (int*)  (ws + 219316224);
  int*   counts  = (int*)(ws + 219381760);
  int*   offsets = counts + 8;
  int*   cursors = counts + 16;

  router_kernel<<<2048, 256, 0, stream>>>(hs, rw, rb, xb, sel, gate, pprob, pcnt);
  tcvt2_kernel<<<dim3(1024, 16), 256, 0, stream>>>(w1, w2, w1t, w2t);
  reduce_kernel<<<1, 256, 0, stream>>>(pprob, pcnt, 2048, counts, offsets, cursors,
                                       out + (out_size - 1));
  scatter_kernel<<<32, 256, 0, stream>>>(sel, offsets, cursors, idxl);
  gemm1_kernel<<<dim3(32, 64, 8), 256, 0, stream>>>(xb, w1t, b1, idxl, counts, offsets, hbuf);
  gemm2_kernel<<<dim3(8, 64, 8), 512, 0, stream>>>(hbuf, w2t, b2, idxl, gate, counts, offsets, out);
}